// Round 9
// baseline (45.873 us; speedup 1.0000x reference)
//
#include <hip/hip_runtime.h>

// CARAFE naive upsample: N=2, C=256, H=100, W=100, K=5, G=1, S=2.
// out[n,c,2h+a,2w+b] = sum_{dy,dx} mask[n,dy*5+dx,2h+a,2w+b] * feat[n,c,h+dy-2,w+dx-2]
//
// R1: full 25-tap unroll -> 256 VGPR, latency-bound. 80.7 us.
// R2: (256,4) cap -> scratch spills. 708 us.
// R3: unroll-1 dy loop. 50.1 us.
// R4: clamp+mask-zero, L1 features. 47.2 us.
// R5: LDS channels-last. 45.2 us (2.78M bank conflicts, stride 0 mod 8).
// R6: pixel-pair v1. 52.7 us REGRESSION: staging wrote b32 at swizzled
//     stride (4-way write conflict) + halved block count.
// R7: bad RSTR (rows overlapped) -> wrong output.
// R8: RSTR=29 odd, b128 staging writes. 38.1 us, conflicts 1.92M. Budget:
//     LDS issue ~10us + conflicts 3us + mask-L1 6.5us + VALU 7us; VALU 18%,
//     HBM 29% -> instruction-count bound at low occupancy.
// R9: pixel-pair, properly: 128-thr blocks, 10x25 tile (2560 blocks kept),
//     R8-style staging (coalesced gather + consecutive-lane ds_write_b128),
//     read swizzle phys_x = x + (x>>1) (odd wp coeff -> uniform bank
//     phases), masks/stores float4. 30 b128 + 25 mask-f4 per pixel vs
//     50 + 50-f2. RSTR=21, LDS 19.5 KB.

typedef float v4f __attribute__((ext_vector_type(4)));

#define N_ 2
#define C_ 256
#define H_ 100
#define W_ 100
#define CC 8
#define HW_ (H_ * W_)
#define OW_ (W_ * 2)
#define OHW_ (HW_ * 4)
#define NCHUNK (C_ / CC)          // 32
#define TW 10                     // tile x extent (low-res)
#define TH 25                     // tile y extent
#define HXc 14                    // halo cols  (TW+4)
#define HYr 29                    // halo rows  (TH+4)
#define NROW (HYr * 2)            // 58 rows (y x channel-quad)
#define RSTR 21                   // f4 row stride (odd, >= physx_max+1 = 20)
#define NPAIR (TW / 2)            // 5 pixel-pairs per tile row
#define TILES_X (W_ / TW)         // 10
#define TILES_Y (H_ / TH)         // 4
#define TILES (TILES_X * TILES_Y) // 40

__global__ __launch_bounds__(128) void carafe_kernel(
    const float* __restrict__ feat,
    const float* __restrict__ mask,
    float* __restrict__ out) {

    // lds4[row][phys_x]: row = y*2 + cq, phys_x = x + (x>>1). One entry =
    // float4 of channels cq*4..cq*4+3 at spatial (y, x).
    __shared__ v4f lds4[NROW * RSTR];      // 58*21*16 = 19,488 B

    const int cchunk = blockIdx.x;         // chunk-major for mask L2 sharing
    const int tile   = blockIdx.y;
    const int n      = blockIdx.z;
    const int tx = tile % TILES_X;
    const int ty = tile / TILES_X;
    const int x0 = tx * TW;
    const int y0 = ty * TH;
    const int t = threadIdx.x;             // 0..127

    // ---- stage: i-th (row, xcol) pair; 4 channel loads -> ds_write_b128 ----
    {
        const float* fb = feat + (n * C_ + cchunk * CC) * HW_;
#pragma unroll
        for (int r = 0; r < 7; ++r) {
            const int i = r * 128 + t;
            if (i < NROW * HXc) {
                const int row  = i / HXc;      // 0..57
                const int xcol = i % HXc;      // 0..13
                const int y  = row >> 1;
                const int cq = row & 1;
                const int yy = y0 - 2 + y;
                const int xx = x0 - 2 + xcol;
                v4f v = {0.f, 0.f, 0.f, 0.f};
                if (((unsigned)yy < (unsigned)H_) & ((unsigned)xx < (unsigned)W_)) {
                    const int o = (cq * 4) * HW_ + yy * W_ + xx;
                    v.x = fb[o];
                    v.y = fb[o + HW_];
                    v.z = fb[o + 2 * HW_];
                    v.w = fb[o + 3 * HW_];
                }
                const int physx = xcol + (xcol >> 1);
                lds4[row * RSTR + physx] = v;
            }
        }
    }
    __syncthreads();

    if (t >= TH * NPAIR) return;           // 125 compute threads
    const int hl = t / NPAIR;              // 0..24
    const int wp = t % NPAIR;              // 0..4

    v4f a0[CC], a1[CC];                    // [channel]; xyzw = ow0..ow0+3
#pragma unroll
    for (int c = 0; c < CC; ++c) {
        a0[c] = (v4f){0.f, 0.f, 0.f, 0.f};
        a1[c] = (v4f){0.f, 0.f, 0.f, 0.f};
    }

    const int oh0 = 2 * (y0 + hl);
    const int ow0 = 2 * (x0 + 2 * wp);     // multiple of 4 -> f4 aligned
    const float* mbase = mask + n * (25 * OHW_) + oh0 * OW_ + ow0;
    const int base3 = 3 * wp;              // phys_x(2wp+j) = 3wp + j + (j>>1)

#pragma unroll 1
    for (int dy = 0; dy < 5; ++dy) {
        const int p0 = ((hl + dy) * 2) * RSTR + base3;

        v4f fa[6], fbv[6];                 // c0..3 / c4..7 at window pos j
#pragma unroll
        for (int j = 0; j < 6; ++j) {
            const int off = j + (j >> 1);  // 0,1,3,4,6,7
            fa[j]  = lds4[p0 + off];
            fbv[j] = lds4[p0 + RSTR + off];
        }

        const float* mrow = mbase + (dy * 5) * OHW_;
#pragma unroll
        for (int dx = 0; dx < 5; ++dx) {
            const v4f m0 = *reinterpret_cast<const v4f*>(mrow + dx * OHW_);        // a=0
            const v4f m1 = *reinterpret_cast<const v4f*>(mrow + dx * OHW_ + OW_);  // a=1
#pragma unroll
            for (int c = 0; c < CC; ++c) {
                const float fl = (c < 4) ? fa[dx][c]     : fbv[dx][c - 4];      // pixel 0
                const float fr = (c < 4) ? fa[dx + 1][c] : fbv[dx + 1][c - 4];  // pixel 1
                const v4f fv = {fl, fl, fr, fr};
                a0[c] = __builtin_elementwise_fma(fv, m0, a0[c]);   // 2x v_pk_fma_f32
                a1[c] = __builtin_elementwise_fma(fv, m1, a1[c]);
            }
        }
    }

    float* ob = out + (n * C_ + cchunk * CC) * OHW_ + oh0 * OW_ + ow0;
#pragma unroll
    for (int c = 0; c < CC; ++c) {
        *reinterpret_cast<v4f*>(ob + c * OHW_)       = a0[c];
        *reinterpret_cast<v4f*>(ob + c * OHW_ + OW_) = a1[c];
    }
}

extern "C" void kernel_launch(void* const* d_in, const int* in_sizes, int n_in,
                              void* d_out, int out_size, void* d_ws, size_t ws_size,
                              hipStream_t stream) {
    const float* feat = (const float*)d_in[0];
    const float* mask = (const float*)d_in[1];
    float* out = (float*)d_out;

    dim3 grid(NCHUNK, TILES, N_);   // 32 x 40 x 2 = 2560 blocks of 128
    carafe_kernel<<<grid, 128, 0, stream>>>(feat, mask, out);
}

// Round 10
// 42.120 us; speedup vs baseline: 1.0891x; 1.0891x over previous
//
#include <hip/hip_runtime.h>

// CARAFE naive upsample: N=2, C=256, H=100, W=100, K=5, G=1, S=2.
// out[n,c,2h+a,2w+b] = sum_{dy,dx} mask[n,dy*5+dx,2h+a,2w+b] * feat[n,c,h+dy-2,w+dx-2]
//
// R1: full 25-tap unroll -> 256 VGPR, latency-bound. 80.7 us.
// R2: (256,4) cap -> scratch spills. 708 us.
// R3: unroll-1 dy loop. 50.1 us.
// R4: clamp+mask-zero, L1 features. 47.2 us.
// R5: LDS channels-last. 45.2 us.
// R6/R9: pixel-pair variants. 52.7/45.9 us REGRESSIONS — both halved total
//     wave count (R6: blocks, R9: waves/block). Kernel is concurrency-bound:
//     all pipes <30%, per-pipe work ~balanced; serial sum = 38us, overlapped
//     = ~20us. Wave count >> instruction count.
// R8: RSTR=29 odd, b128 staging. 38.1 us. Occupancy ~10 waves/CU.
// R10: wave-private tiles, BARRIER-FREE. Wave64 owns an 8x8-pixel tile x
//     8 channels: stages its 12x12 halo into a private 4.9KB LDS slice,
//     s_waitcnt lgkmcnt(0) (no __syncthreads), computes. Block = 4 waves =
//     4 chunks of the SAME tile -> same masks -> mask L1 traffic /4.
//     2704 blocks x 4 waves = 42 waves/CU offered (vs 10).

typedef float v2f __attribute__((ext_vector_type(2)));
typedef float v4f __attribute__((ext_vector_type(4)));

#define N_ 2
#define C_ 256
#define H_ 100
#define W_ 100
#define HW_ (H_ * W_)
#define OW_ (W_ * 2)
#define OHW_ (HW_ * 4)
#define TS 8                       // pixels per tile side (per wave)
#define HT 12                      // halo extent = TS+4
#define NT 13                      // tiles per side: 13*8 = 104 >= 100
#define RSTR 13                    // f4 stride of one y-row (odd)
#define QOFF (HT * RSTR)           // 156: offset of channel-quad 1
#define WSZ (2 * QOFF)             // 312 f4 per wave region

__global__ __launch_bounds__(256) void carafe_kernel(
    const float* __restrict__ feat,
    const float* __restrict__ mask,
    float* __restrict__ out) {

    __shared__ v4f lds[4 * WSZ];            // 4 waves x 4,992 B = 19,968 B

    const int t    = threadIdx.x;
    const int wv   = t >> 6;                // wave 0..3
    const int lane = t & 63;
    const int chunk = blockIdx.x * 4 + wv;  // 0..31 (8 channels each)
    const int ti = blockIdx.y;              // 0..168
    const int n  = blockIdx.z;
    const int tx = ti % NT, ty = ti / NT;
    const int x0 = tx * TS, y0 = ty * TS;

    v4f* wl = lds + wv * WSZ;
    const float* fb = feat + (n * C_ + chunk * 8) * HW_;

    // ---- stage 2 quads x 12 x 12 halo (288 items), wave-private ----
#pragma unroll
    for (int r = 0; r < 5; ++r) {
        const int i = r * 64 + lane;
        if (i < 2 * HT * HT) {
            const int q   = i / (HT * HT);
            const int rem = i % (HT * HT);
            const int y   = rem / HT;
            const int col = rem % HT;
            const int yy = y0 - 2 + y;
            const int xx = x0 - 2 + col;
            v4f v = {0.f, 0.f, 0.f, 0.f};
            if (((unsigned)yy < (unsigned)H_) & ((unsigned)xx < (unsigned)W_)) {
                const int o = (q * 4) * HW_ + yy * W_ + xx;
                v.x = fb[o];
                v.y = fb[o + HW_];
                v.z = fb[o + 2 * HW_];
                v.w = fb[o + 3 * HW_];
            }
            wl[q * QOFF + y * RSTR + col] = v;
        }
    }
    // Same-wave RAW through LDS: wait for our ds_writes; no block barrier.
    asm volatile("s_waitcnt lgkmcnt(0)" ::: "memory");

    // ---- compute: lane -> pixel (py,px) of the 8x8 tile ----
    const int py = lane >> 3, px = lane & 7;
    const int h  = y0 + py, wpix = x0 + px;
    const bool alive = (h < H_) & (wpix < W_);
    const int hc = min(h, H_ - 1), wc = min(wpix, W_ - 1);   // clamp for dead lanes
    const int oh0 = 2 * hc, ow0 = 2 * wc;
    const float* mbase = mask + n * (25 * OHW_) + oh0 * OW_ + ow0;

    v2f a0[8], a1[8];
#pragma unroll
    for (int c = 0; c < 8; ++c) { a0[c] = (v2f){0.f, 0.f}; a1[c] = (v2f){0.f, 0.f}; }

#pragma unroll 2
    for (int dy = 0; dy < 5; ++dy) {
        const float* mrow = mbase + (dy * 5) * OHW_;
        const int rb = (py + dy) * RSTR + px;
#pragma unroll
        for (int dx = 0; dx < 5; ++dx) {
            const v2f m0 = *reinterpret_cast<const v2f*>(mrow + dx * OHW_);        // a=0
            const v2f m1 = *reinterpret_cast<const v2f*>(mrow + dx * OHW_ + OW_);  // a=1
            const v4f lo = wl[rb + dx];          // c0..3
            const v4f hi = wl[QOFF + rb + dx];   // c4..7
            const float f[8] = {lo.x, lo.y, lo.z, lo.w, hi.x, hi.y, hi.z, hi.w};
#pragma unroll
            for (int c = 0; c < 8; ++c) {
                const v2f fv = {f[c], f[c]};
                a0[c] = __builtin_elementwise_fma(fv, m0, a0[c]);   // v_pk_fma_f32
                a1[c] = __builtin_elementwise_fma(fv, m1, a1[c]);
            }
        }
    }

    if (alive) {
        float* ob = out + (n * C_ + chunk * 8) * OHW_ + oh0 * OW_ + ow0;
#pragma unroll
        for (int c = 0; c < 8; ++c) {
            *reinterpret_cast<v2f*>(ob + c * OHW_)       = a0[c];
            *reinterpret_cast<v2f*>(ob + c * OHW_ + OW_) = a1[c];
        }
    }
}

extern "C" void kernel_launch(void* const* d_in, const int* in_sizes, int n_in,
                              void* d_out, int out_size, void* d_ws, size_t ws_size,
                              hipStream_t stream) {
    const float* feat = (const float*)d_in[0];
    const float* mask = (const float*)d_in[1];
    float* out = (float*)d_out;

    dim3 grid(8, NT * NT, N_);   // 8 chunk-quads x 169 tiles x 2 = 2704 blocks
    carafe_kernel<<<grid, 256, 0, stream>>>(feat, mask, out);
}

// Round 11
// 39.176 us; speedup vs baseline: 1.1710x; 1.0752x over previous
//
#include <hip/hip_runtime.h>

// CARAFE naive upsample: N=2, C=256, H=100, W=100, K=5, G=1, S=2.
// out[n,c,2h+a,2w+b] = sum_{dy,dx} mask[n,dy*5+dx,2h+a,2w+b] * feat[n,c,h+dy-2,w+dx-2]
//
// R1: full 25-tap unroll -> 256 VGPR, latency-bound. 80.7 us.
// R2: (256,4) cap -> scratch spills. 708 us.
// R3: unroll-1 dy loop. 50.1 us.
// R4: clamp+mask-zero, L1 features. 47.2 us.
// R5: LDS channels-last. 45.2 us.
// R6/R9/R10: pixel-pair / wave-private variants. 52.7/45.9/42.1 us — all
//     regressions. Geometry is not the lever.
// R8: RSTR=29 odd, b128 staging. 38.1 us. ANCHOR. VGPR=52: compiler
//     register-starved the loop -> every load consumed immediately, no MLP;
//     avg wave lifetime ~10us for ~350 instrs (~70 stall cyc/instr); all
//     pipes <30%.
// R11: R8 + per-dy BATCHED loads: issue all 10 mask loads first (longest
//     latency), then all 10 ds_read_b128, then the 80 FMAs. ~20 loads in
//     flight per dy instead of ~2. unroll-1 dy keeps VGPR ~105 (4 w/SIMD).

typedef float v2f __attribute__((ext_vector_type(2)));

#define N_ 2
#define C_ 256
#define H_ 100
#define W_ 100
#define CC 8
#define HW_ (H_ * W_)
#define OW_ (W_ * 2)
#define OHW_ (HW_ * 4)
#define NCHUNK (C_ / CC)          // 32
#define TW 25
#define TH 10
#define HX 29                     // halo cols (TW+4)
#define NROW 28                   // 14 halo rows x 2 channel-quads
#define RSTR 29                   // float4 row stride: >= HX and odd
#define TILES_X (W_ / TW)         // 4
#define TILES_Y (H_ / TH)         // 10
#define TILES (TILES_X * TILES_Y) // 40

__global__ __launch_bounds__(256) void carafe_kernel(
    const float* __restrict__ feat,
    const float* __restrict__ mask,
    float* __restrict__ out) {

    // row p = y*2 + cq (y: halo row 0..13, cq: channel quad); float4 index
    // p*29 + x, innermost c%4.
    __shared__ float4 lds4[NROW * RSTR];   // 28*29*16 = 12,992 B

    const int cchunk = blockIdx.x;         // chunk-major: 32 blocks sharing a
    const int tile   = blockIdx.y;         // tile's mask slice dispatch together
    const int n      = blockIdx.z;
    const int tx = tile % TILES_X;
    const int ty = tile / TILES_X;
    const int x0 = tx * TW;
    const int y0 = ty * TH;
    const int t = threadIdx.x;
    const int lane = t & 31;
    const int g = t >> 5;                  // 8 groups

    // ---- stage: thread gathers 4 channels at (yy, xx), writes one float4 ----
    {
        const float* fb = feat + (n * C_ + cchunk * CC) * HW_;
        const int xx = x0 - 2 + lane;
        const bool xok = (lane < HX) & ((unsigned)xx < (unsigned)W_);
#pragma unroll
        for (int r = 0; r < 4; ++r) {
            const int p = g * 4 + r;       // 0..31, active < 28
            const int y = p >> 1;
            const int cq = p & 1;
            const int yy = y0 - 2 + y;
            float v0 = 0.f, v1 = 0.f, v2 = 0.f, v3 = 0.f;
            if (xok & ((unsigned)yy < (unsigned)H_) & (p < NROW)) {
                const int o = (cq * 4) * HW_ + yy * W_ + xx;
                v0 = fb[o];
                v1 = fb[o + HW_];
                v2 = fb[o + 2 * HW_];
                v3 = fb[o + 3 * HW_];
            }
            if ((p < NROW) & (lane < HX))
                lds4[p * RSTR + lane] = make_float4(v0, v1, v2, v3);
        }
    }
    __syncthreads();

    if (t >= TH * TW) return;              // 250 compute threads
    const int hl = t / TW;
    const int wl = t % TW;

    v2f a0[CC], a1[CC];
#pragma unroll
    for (int c = 0; c < CC; ++c) { a0[c] = (v2f){0.f, 0.f}; a1[c] = (v2f){0.f, 0.f}; }

    const int oh0 = 2 * (y0 + hl);
    const int ow0 = 2 * (x0 + wl);
    const float* mbase = mask + n * (25 * OHW_) + oh0 * OW_ + ow0;

#pragma unroll 1
    for (int dy = 0; dy < 5; ++dy) {
        const int ry = (hl + dy) * 2;
        const float* mrow = mbase + (dy * 5) * OHW_;

        // ---- batch-issue all global mask loads first (longest latency) ----
        v2f m0[5], m1[5];
#pragma unroll
        for (int dx = 0; dx < 5; ++dx) {
            m0[dx] = *reinterpret_cast<const v2f*>(mrow + dx * OHW_);        // a=0
            m1[dx] = *reinterpret_cast<const v2f*>(mrow + dx * OHW_ + OW_);  // a=1
        }

        // ---- then all LDS reads ----
        float4 lo[5], hi[5];
#pragma unroll
        for (int dx = 0; dx < 5; ++dx) {
            lo[dx] = lds4[ry * RSTR + wl + dx];        // c0..3
            hi[dx] = lds4[(ry + 1) * RSTR + wl + dx];  // c4..7
        }

        // ---- then the 80 FMAs ----
#pragma unroll
        for (int dx = 0; dx < 5; ++dx) {
            const float f[8] = {lo[dx].x, lo[dx].y, lo[dx].z, lo[dx].w,
                                hi[dx].x, hi[dx].y, hi[dx].z, hi[dx].w};
#pragma unroll
            for (int c = 0; c < CC; ++c) {
                const v2f fv = {f[c], f[c]};
                a0[c] = __builtin_elementwise_fma(fv, m0[dx], a0[c]);   // v_pk_fma_f32
                a1[c] = __builtin_elementwise_fma(fv, m1[dx], a1[c]);
            }
        }
    }

    float* ob = out + (n * C_ + cchunk * CC) * OHW_ + oh0 * OW_ + ow0;
#pragma unroll
    for (int c = 0; c < CC; ++c) {
        *reinterpret_cast<v2f*>(ob + c * OHW_) = a0[c];
        *reinterpret_cast<v2f*>(ob + c * OHW_ + OW_) = a1[c];
    }
}

extern "C" void kernel_launch(void* const* d_in, const int* in_sizes, int n_in,
                              void* d_out, int out_size, void* d_ws, size_t ws_size,
                              hipStream_t stream) {
    const float* feat = (const float*)d_in[0];
    const float* mask = (const float*)d_in[1];
    float* out = (float*)d_out;

    dim3 grid(NCHUNK, TILES, N_);   // 32 x 40 x 2 = 2560 blocks
    carafe_kernel<<<grid, 256, 0, stream>>>(feat, mask, out);
}